// Round 9
// baseline (78.920 us; speedup 1.0000x reference)
//
#include <hip/hip_runtime.h>
#include <math.h>

#define NFFT     1024
#define HOP      256
#define NFRAMES  622
#define NBATCH   32
#define XLEN     160000
#define TILE_T   16
#define NPAIR    8
#define ROW      1234            // padded float2 stride per array (R5-verified)
#define KBINS    513
#define NT       512
#define NTILES   39              // tiles per batch row
#define NBLK     512             // 2 persistent blocks per CU
#define CHUNK    156             // tiles per XCD (1248/8)

// multi-digit pad (float2 units): PAD(i) = i + 2(i>>4) + 4(i>>6) + 8(i>>8).
#define PAD(i)   ((i) + 2*((i)>>4) + 4*((i)>>6) + 8*((i)>>8))

#define C1 0.9238795325112867f   // cos(pi/8)
#define S1 0.3826834323650898f   // sin(pi/8)
#define C2 0.7071067811865476f   // cos(pi/4)

__device__ __forceinline__ float2 cmul(float2 a, float2 b) {
    return make_float2(a.x*b.x - a.y*b.y, a.x*b.y + a.y*b.x);
}
__device__ __forceinline__ float2 csqr(float2 a) {
    return make_float2(a.x*a.x - a.y*a.y, 2.0f*a.x*a.y);
}

// hardware sin/cos: input in REVOLUTIONS; args < 0.25 so no range reduction.
__device__ __forceinline__ float2 w_of_rev(float f) {
    float s, c;
    asm("v_sin_f32 %0, %1" : "=v"(s) : "v"(f));
    asm("v_cos_f32 %0, %1" : "=v"(c) : "v"(f));
    return make_float2(c, s);
}

__device__ __forceinline__ void bfly4(float2& a, float2& b, float2& c, float2& d,
                                      float2 w1, float2 w2, float2 w3) {
    float2 apc = make_float2(a.x + c.x, a.y + c.y);
    float2 amc = make_float2(a.x - c.x, a.y - c.y);
    float2 bpd = make_float2(b.x + d.x, b.y + d.y);
    float2 bmd = make_float2(b.x - d.x, b.y - d.y);
    float2 y0 = make_float2(apc.x + bpd.x, apc.y + bpd.y);
    float2 y2 = make_float2(apc.x - bpd.x, apc.y - bpd.y);
    float2 y1 = make_float2(amc.x + bmd.y, amc.y - bmd.x);  // amc - i*bmd
    float2 y3 = make_float2(amc.x - bmd.y, amc.y + bmd.x);  // amc + i*bmd
    a = y0; b = cmul(w1, y1); c = cmul(w2, y2); d = cmul(w3, y3);
}
__device__ __forceinline__ void bfly4_nw(float2& a, float2& b, float2& c, float2& d) {
    float2 apc = make_float2(a.x + c.x, a.y + c.y);
    float2 amc = make_float2(a.x - c.x, a.y - c.y);
    float2 bpd = make_float2(b.x + d.x, b.y + d.y);
    float2 bmd = make_float2(b.x - d.x, b.y - d.y);
    a = make_float2(apc.x + bpd.x, apc.y + bpd.y);
    b = make_float2(amc.x + bmd.y, amc.y - bmd.x);
    c = make_float2(apc.x - bpd.x, apc.y - bpd.y);
    d = make_float2(amc.x - bmd.y, amc.y + bmd.x);
}

// wave-internal LDS ordering fence (HW keeps a wave's DS ops in order;
// pins the compiler; rule #18: sched_barrier after the inline-asm waitcnt).
__device__ __forceinline__ void fence() {
    asm volatile("s_waitcnt lgkmcnt(0)" ::: "memory");
    __builtin_amdgcn_sched_barrier(0);
}
// block barrier WITHOUT vmcnt drain: each wave drains its own LDS queue,
// then s_barrier. Outstanding global loads (prefetch) / stores keep flowing.
__device__ __forceinline__ void lgk_barrier() {
    __builtin_amdgcn_sched_barrier(0);
    asm volatile("s_waitcnt lgkmcnt(0)" ::: "memory");
    __builtin_amdgcn_s_barrier();
    __builtin_amdgcn_sched_barrier(0);
}

// ~17-instr atan2: v_rcp (1 ulp) + deg-11 minimax odd poly, err ~5e-6 rad.
// Signed-zero-correct via copysign; mx==0 guard handles atan2(0,0).
__device__ __forceinline__ float fast_atan2f(float y, float x) {
    const float ax = fabsf(x), ay = fabsf(y);
    const float mx = fmaxf(ax, ay), mn = fminf(ax, ay);
    float r = mn * __builtin_amdgcn_rcpf(mx);
    if (mx == 0.0f) r = 0.0f;
    const float t = r * r;
    float p = fmaf(t, -0.01172120f, 0.05265332f);
    p = fmaf(t, p, -0.11643287f);
    p = fmaf(t, p, 0.19354346f);
    p = fmaf(t, p, -0.33262347f);
    p = fmaf(t, p, 0.99997726f);
    float a = r * p;
    a = (ay > ax) ? (1.5707963267948966f - a) : a;
    a = (x < 0.0f) ? (3.14159265358979323f - a) : a;
    return copysignf(a, y);
}

// exact /39 for 0 <= v < 2496 (verified at 38/39/78/1208/1209/1247)
__device__ __forceinline__ int div39(int v) { return (v * 26887) >> 20; }

__global__ __launch_bounds__(NT, 4)
void spec_kernel(const float* __restrict__ x, const float* __restrict__ win,
                 float* __restrict__ out)
{
    __shared__ __align__(16) float2 zb[NPAIR * ROW];  // 78,976 B -> 2 blocks/CU

    const int tid = threadIdx.x;
    const int wv  = tid >> 6;     // wave id == packed-array id
    const int ln  = tid & 63;

    // static epoch-strided tile map: XCD c owns tiles [156c, 156c+156);
    // per epoch e its 64 blocks run 64 CONSECUTIVE tiles concurrently
    // (keeps 128-B output-line halves concurrent -> L2 write merge).
    const int xcd = blockIdx.x & 7;
    const int lb  = blockIdx.x >> 3;          // 0..63 (local block on XCD)
    const int chunk = CHUNK * xcd;

    float4 pa[4], pb[4];
    // ---- initial prefetch (epoch 0 tile) ----
    {
        const int tile = chunk + lb;
        const int bb = div39(tile);
        const int t0 = (tile - 39*bb) * TILE_T;
        const float* xb = x + (size_t)bb * XLEN;
        const int f0 = t0 + 2*wv, f1 = f0 + 1;
        const bool v0 = (f0 < NFRAMES), v1 = (f1 < NFRAMES);
        #pragma unroll
        for (int q = 0; q < 4; ++q) {
            const int n0 = (q << 8) + (ln << 2);
            pa[q] = v0 ? *reinterpret_cast<const float4*>(&xb[f0*HOP + n0])
                       : make_float4(0.f,0.f,0.f,0.f);
            pb[q] = v1 ? *reinterpret_cast<const float4*>(&xb[f1*HOP + n0])
                       : make_float4(0.f,0.f,0.f,0.f);
        }
    }

    for (int e = 0;; ++e) {
        const int tl = 64*e + lb;
        if (tl >= CHUNK) break;
        const int tile = chunk + tl;
        const int bb = div39(tile);
        const int t0 = (tile - 39*bb) * TILE_T;

        // ---- window + stage own array to LDS (consumes pa/pb) ----
        {
            float4* D4 = reinterpret_cast<float4*>(
                &zb[wv*ROW + 4*ln + 2*(ln>>2) + 4*(ln>>4)]);
            #pragma unroll
            for (int q = 0; q < 4; ++q) {
                const int n0 = (q << 8) + (ln << 2);
                const float4 w4 = *reinterpret_cast<const float4*>(&win[n0]);
                D4[156*q]     = make_float4(w4.x*pa[q].x, w4.x*pb[q].x,
                                            w4.y*pa[q].y, w4.y*pb[q].y);
                D4[156*q + 1] = make_float4(w4.z*pa[q].z, w4.z*pb[q].z,
                                            w4.w*pa[q].w, w4.w*pb[q].w);
            }
        }
        fence();

        // ---- fused stages 0+1 (radix-16 in registers) ----
        {
            float2* p = &zb[wv*ROW + ln + 2*(ln>>4)];
            float2 E[16];
            #pragma unroll
            for (int j = 0; j < 16; ++j) E[j] = p[76*j + 8*(j>>2)];
            const float2 wc = w_of_rev((float)ln * (-1.0f/1024.0f));   // W_1024^ln
            #pragma unroll
            for (int q = 0; q < 4; ++q) {
                float2 w1;
                if      (q == 0) w1 = wc;
                else if (q == 1) w1 = cmul(wc, make_float2(C1, -S1));
                else if (q == 2) w1 = cmul(wc, make_float2(C2, -C2));
                else             w1 = cmul(wc, make_float2(S1, -C1));
                float2 w2 = csqr(w1), w3 = cmul(w1, w2);
                bfly4(E[q], E[q+4], E[q+8], E[q+12], w1, w2, w3);
            }
            const float2 wb  = csqr(csqr(wc));                         // W_1024^{4ln}
            const float2 wb2 = csqr(wb), wb3 = cmul(wb, wb2);
            #pragma unroll
            for (int u = 0; u < 4; ++u)
                bfly4(E[4*u], E[4*u+1], E[4*u+2], E[4*u+3], wb, wb2, wb3);
            #pragma unroll
            for (int j = 0; j < 16; ++j) p[76*j + 8*(j>>2)] = E[j];
        }
        fence();

        // ---- stage 2 (M=16) ----
        {
            const int m = ln & 15, h = ln >> 4;
            float2* p = &zb[wv*ROW + 76*h + m];
            const float2 w1 = w_of_rev((float)m * (-1.0f/64.0f));      // W_64^m
            const float2 w2 = csqr(w1), w3 = cmul(w1, w2);
            #pragma unroll
            for (int u = 0; u < 4; ++u) {
                float2 a  = p[312*u],      b2 = p[312*u + 18];
                float2 c2 = p[312*u + 36], d2 = p[312*u + 54];
                bfly4(a, b2, c2, d2, w1, w2, w3);
                p[312*u]      = a;   p[312*u + 18] = b2;
                p[312*u + 36] = c2;  p[312*u + 54] = d2;
            }
        }
        fence();

        // ---- fused stages 3+4 (registers, constant twiddles), b128 ----
        {
            float4* p = reinterpret_cast<float4*>(
                &zb[wv*ROW + 18*ln + 4*(ln>>2) + 8*(ln>>4)]);
            float2 F[16];
            #pragma unroll
            for (int r = 0; r < 8; ++r) {
                const float4 v = p[r];
                F[2*r]   = make_float2(v.x, v.y);
                F[2*r+1] = make_float2(v.z, v.w);
            }
            bfly4_nw(F[0], F[4], F[8],  F[12]);
            bfly4(F[1], F[5], F[9],  F[13], make_float2(C1,-S1), make_float2(C2,-C2), make_float2(S1,-C1));
            bfly4(F[2], F[6], F[10], F[14], make_float2(C2,-C2), make_float2(0.f,-1.f), make_float2(-C2,-C2));
            bfly4(F[3], F[7], F[11], F[15], make_float2(S1,-C1), make_float2(-C2,-C2), make_float2(-C1, S1));
            bfly4_nw(F[0],  F[1],  F[2],  F[3]);
            bfly4_nw(F[4],  F[5],  F[6],  F[7]);
            bfly4_nw(F[8],  F[9],  F[10], F[11]);
            bfly4_nw(F[12], F[13], F[14], F[15]);
            #pragma unroll
            for (int r = 0; r < 8; ++r)
                p[r] = make_float4(F[2*r].x, F[2*r].y, F[2*r+1].x, F[2*r+1].y);
        }
        lgk_barrier();   // publish all arrays (no vmcnt drain)

        // ---- prefetch next epoch's x into registers (retires under output) ----
        {
            const int ntl = 64*(e+1) + lb;
            if (ntl < CHUNK) {
                const int ntile = chunk + ntl;
                const int nb  = div39(ntile);
                const int nt0 = (ntile - 39*nb) * TILE_T;
                const float* xb = x + (size_t)nb * XLEN;
                const int f0 = nt0 + 2*wv, f1 = f0 + 1;
                const bool v0 = (f0 < NFRAMES), v1 = (f1 < NFRAMES);
                #pragma unroll
                for (int q = 0; q < 4; ++q) {
                    const int n0 = (q << 8) + (ln << 2);
                    pa[q] = v0 ? *reinterpret_cast<const float4*>(&xb[f0*HOP + n0])
                               : make_float4(0.f,0.f,0.f,0.f);
                    pb[q] = v1 ? *reinterpret_cast<const float4*>(&xb[f1*HOP + n0])
                               : make_float4(0.f,0.f,0.f,0.f);
                }
            }
        }

        // ---- output: unpack + mag/phase; 64-B write runs per (k, tile) ----
        {
            const int kg  = tid >> 3;          // 0..63
            const int jj  = tid & 7;           // array == frame pair
            const int t_e = t0 + 2*jj;
            const bool tval = (t_e < NFRAMES);

            const int R1 = ((kg & 3) << 8) | ((kg & 12) << 4) | (kg & 48);
            const int km = 64 - kg;
            const int R2 = ((km & 3) << 8) | ((km & 12) << 4) | (km & 48);
            const int J0 = (kg == 0) ? 16 : 15;
            const float2* zp1 = &zb[jj*ROW + PAD(R1)];
            const float2* zp2 = &zb[jj*ROW + PAD(R2)];

            float* magp = out;                                        // [32][513][622]
            float* php  = out + (size_t)NBATCH * KBINS * NFRAMES;     // [32][1024][622]
            const size_t magbase = (size_t)bb * KBINS * NFRAMES + t_e;
            const size_t phbase  = (size_t)bb * NFFT  * NFRAMES + t_e;

            if (tval) {
                #pragma unroll
                for (int it = 0; it < 9; ++it) {
                    if (it == 8 && kg != 0) break;          // only k=512 remains
                    const int k  = kg + (it << 6);
                    const int c1 = ((it & 3) << 2) | (it >> 2);   // rev4(64it)
                    const int j2 = (J0 - it) & 15;
                    const int c2 = ((j2 & 3) << 2) | (j2 >> 2);
                    const float2 z1 = zp1[c1];
                    const float2 z2 = zp2[c2];
                    // F_even[k]=(Z[k]+conj(Z[N-k]))/2 ; F_odd[k]=-i(Z[k]-conj(Z[N-k]))/2
                    const float re_e = 0.5f*(z1.x + z2.x);
                    const float im_e = 0.5f*(z1.y - z2.y);  // exact +0.0 at k=0,512
                    const float re_o = 0.5f*(z1.y + z2.y);
                    const float im_o = 0.5f*(z2.x - z1.x);
                    *reinterpret_cast<float2*>(&magp[magbase + (size_t)k * NFRAMES]) =
                        make_float2(fmaf(re_e, re_e, im_e*im_e),
                                    fmaf(re_o, re_o, im_o*im_o));
                    const float ph_e = fast_atan2f(im_e, re_e);
                    const float ph_o = fast_atan2f(im_o, re_o);
                    *reinterpret_cast<float2*>(&php[phbase + (size_t)k * NFRAMES]) =
                        make_float2(ph_e, ph_o);
                    if (k != 0 && k != 512) {
                        // atan2 odd in y INCLUDING signed zeros -> sign flip
                        *reinterpret_cast<float2*>(&php[phbase + (size_t)(NFFT - k) * NFRAMES]) =
                            make_float2(-ph_e, -ph_o);
                    }
                }
            }
        }
        lgk_barrier();   // output LDS reads done -> safe to overwrite zb
    }
}

extern "C" void kernel_launch(void* const* d_in, const int* in_sizes, int n_in,
                              void* d_out, int out_size, void* d_ws, size_t ws_size,
                              hipStream_t stream) {
    const float* x  = (const float*)d_in[0];
    const float* rw = (const float*)d_in[1];   // row 0 = fp32 hanning window
    float* out = (float*)d_out;
    spec_kernel<<<dim3(NBLK, 1, 1), dim3(NT, 1, 1), 0, stream>>>(x, rw, out);
}

// Round 10
// 38.587 us; speedup vs baseline: 2.0452x; 2.0452x over previous
//
#include <hip/hip_runtime.h>
#include <math.h>

#define NFFT     1024
#define HOP      256
#define NFRAMES  622
#define NBATCH   32
#define XLEN     160000
#define TILE_T   16
#define NPAIR    8
#define ROW      1234      // padded float2 stride per array (R5-verified)
#define KBINS    513
#define NT       512
#define NTILES   39        // ceil(622/16)
#define NBLK     (NTILES*NBATCH)   // 1248 = 8*156 exactly (bijective XCD swizzle)

// multi-digit pad (float2 units): PAD(i) = i + 2(i>>4) + 4(i>>6) + 8(i>>8).
#define PAD(i)   ((i) + 2*((i)>>4) + 4*((i)>>6) + 8*((i)>>8))

#define C1 0.9238795325112867f   // cos(pi/8)
#define S1 0.3826834323650898f   // sin(pi/8)
#define C2 0.7071067811865476f   // cos(pi/4)

__device__ __forceinline__ float2 cmul(float2 a, float2 b) {
    return make_float2(a.x*b.x - a.y*b.y, a.x*b.y + a.y*b.x);
}
__device__ __forceinline__ float2 csqr(float2 a) {
    return make_float2(a.x*a.x - a.y*a.y, 2.0f*a.x*a.y);
}

// hardware sin/cos: input in REVOLUTIONS; args < 0.25 so no range reduction.
__device__ __forceinline__ float2 w_of_rev(float f) {
    float s, c;
    asm("v_sin_f32 %0, %1" : "=v"(s) : "v"(f));
    asm("v_cos_f32 %0, %1" : "=v"(c) : "v"(f));
    return make_float2(c, s);
}

__device__ __forceinline__ void bfly4(float2& a, float2& b, float2& c, float2& d,
                                      float2 w1, float2 w2, float2 w3) {
    float2 apc = make_float2(a.x + c.x, a.y + c.y);
    float2 amc = make_float2(a.x - c.x, a.y - c.y);
    float2 bpd = make_float2(b.x + d.x, b.y + d.y);
    float2 bmd = make_float2(b.x - d.x, b.y - d.y);
    float2 y0 = make_float2(apc.x + bpd.x, apc.y + bpd.y);
    float2 y2 = make_float2(apc.x - bpd.x, apc.y - bpd.y);
    float2 y1 = make_float2(amc.x + bmd.y, amc.y - bmd.x);  // amc - i*bmd
    float2 y3 = make_float2(amc.x - bmd.y, amc.y + bmd.x);  // amc + i*bmd
    a = y0; b = cmul(w1, y1); c = cmul(w2, y2); d = cmul(w3, y3);
}
__device__ __forceinline__ void bfly4_nw(float2& a, float2& b, float2& c, float2& d) {
    float2 apc = make_float2(a.x + c.x, a.y + c.y);
    float2 amc = make_float2(a.x - c.x, a.y - c.y);
    float2 bpd = make_float2(b.x + d.x, b.y + d.y);
    float2 bmd = make_float2(b.x - d.x, b.y - d.y);
    a = make_float2(apc.x + bpd.x, apc.y + bpd.y);
    b = make_float2(amc.x + bmd.y, amc.y - bmd.x);
    c = make_float2(apc.x - bpd.x, apc.y - bpd.y);
    d = make_float2(amc.x - bmd.y, amc.y + bmd.x);
}

// wave-internal LDS ordering fence (HW keeps a wave's DS ops in order;
// pins the compiler; rule #18: sched_barrier after the inline-asm waitcnt).
__device__ __forceinline__ void fence() {
    asm volatile("s_waitcnt lgkmcnt(0)" ::: "memory");
    __builtin_amdgcn_sched_barrier(0);
}

// ~17-instr atan2: v_rcp (1 ulp) + deg-11 minimax odd poly, err ~5e-6 rad.
// Signed-zero-correct via copysign; mx==0 guard handles atan2(0,0).
__device__ __forceinline__ float fast_atan2f(float y, float x) {
    const float ax = fabsf(x), ay = fabsf(y);
    const float mx = fmaxf(ax, ay), mn = fminf(ax, ay);
    float r = mn * __builtin_amdgcn_rcpf(mx);
    if (mx == 0.0f) r = 0.0f;
    const float t = r * r;
    float p = fmaf(t, -0.01172120f, 0.05265332f);
    p = fmaf(t, p, -0.11643287f);
    p = fmaf(t, p, 0.19354346f);
    p = fmaf(t, p, -0.33262347f);
    p = fmaf(t, p, 0.99997726f);
    float a = r * p;
    a = (ay > ax) ? (1.5707963267948966f - a) : a;
    a = (x < 0.0f) ? (3.14159265358979323f - a) : a;
    return copysignf(a, y);
}

__global__ __launch_bounds__(NT, 4)
void spec_kernel(const float* __restrict__ x, const float* __restrict__ win,
                 float* __restrict__ out)
{
    __shared__ __align__(16) float2 zb[NPAIR * ROW];  // 78,976 B -> 2 blocks/CU

    const int tid = threadIdx.x;
    // R5's proven XCD-chunked swizzle: consecutive hw-adjacent blocks on one
    // XCD process consecutive tiles -> sliding window preserves L2 read reuse
    // AND concurrent 128-B output-line halves (write merge).
    const int lg  = (blockIdx.x & 7) * (NBLK / 8) + (blockIdx.x >> 3);
    const int b   = lg / NTILES;
    const int t0  = (lg - b * NTILES) * TILE_T;
    const int wv  = tid >> 6;     // wave id == packed-array id
    const int ln  = tid & 63;

    // ---- fused load+window+stages 0+1 (radix-16 in registers) ----
    // E[j] = (win[64j+ln]*x[f0*HOP+64j+ln], win[64j+ln]*x[f1*HOP+64j+ln]):
    // b32 loads, 64-lane contiguous (full sectors). No LDS staging round-trip.
    {
        const int f0 = t0 + 2*wv, f1 = f0 + 1;       // wave-uniform
        const float* xb = x + (size_t)b * XLEN;
        const float* x0 = xb + f0*HOP;
        const float* x1 = xb + f1*HOP;
        const bool v0 = (f0 < NFRAMES), v1 = (f1 < NFRAMES);
        float2 E[16];
        #pragma unroll
        for (int j = 0; j < 16; ++j) {
            const int n = (j << 6) + ln;
            const float wn = win[n];
            const float a0 = v0 ? x0[n] : 0.0f;
            const float a1 = v1 ? x1[n] : 0.0f;
            E[j] = make_float2(wn * a0, wn * a1);
        }
        // stage 0: butterflies {m, m+256, m+512, m+768}, m = ln + 64q
        const float2 wc = w_of_rev((float)ln * (-1.0f/1024.0f));   // W_1024^ln
        #pragma unroll
        for (int q = 0; q < 4; ++q) {
            float2 w1;
            if      (q == 0) w1 = wc;
            else if (q == 1) w1 = cmul(wc, make_float2(C1, -S1));   // *W16^1
            else if (q == 2) w1 = cmul(wc, make_float2(C2, -C2));   // *W16^2
            else             w1 = cmul(wc, make_float2(S1, -C1));   // *W16^3
            float2 w2 = csqr(w1), w3 = cmul(w1, w2);
            bfly4(E[q], E[q+4], E[q+8], E[q+12], w1, w2, w3);
        }
        // stage 1: within each 256-block, twiddle W_1024^{4ln}
        const float2 wb  = csqr(csqr(wc));
        const float2 wb2 = csqr(wb), wb3 = cmul(wb, wb2);
        #pragma unroll
        for (int u = 0; u < 4; ++u)
            bfly4(E[4*u], E[4*u+1], E[4*u+2], E[4*u+3], wb, wb2, wb3);
        // first LDS touch: PAD(64j+ln) = PAD(ln) + 76j + 8(j>>2)
        float2* p = &zb[wv*ROW + ln + 2*(ln>>4)];
        #pragma unroll
        for (int j = 0; j < 16; ++j) p[76*j + 8*(j>>2)] = E[j];
    }
    fence();

    // ---- stage 2 (M=16): PAD-base + 312u + 18s ----
    {
        const int m = ln & 15, h = ln >> 4;
        float2* p = &zb[wv*ROW + 76*h + m];
        const float2 w1 = w_of_rev((float)m * (-1.0f/64.0f));      // W_64^m
        const float2 w2 = csqr(w1), w3 = cmul(w1, w2);
        #pragma unroll
        for (int u = 0; u < 4; ++u) {
            float2 a  = p[312*u],      b2 = p[312*u + 18];
            float2 c2 = p[312*u + 36], d2 = p[312*u + 54];
            bfly4(a, b2, c2, d2, w1, w2, w3);
            p[312*u]      = a;   p[312*u + 18] = b2;
            p[312*u + 36] = c2;  p[312*u + 54] = d2;
        }
    }
    fence();

    // ---- fused stages 3+4 (registers, constant twiddles), b128 LDS ----
    {
        float4* p = reinterpret_cast<float4*>(
            &zb[wv*ROW + 18*ln + 4*(ln>>2) + 8*(ln>>4)]);
        float2 F[16];
        #pragma unroll
        for (int r = 0; r < 8; ++r) {
            const float4 v = p[r];
            F[2*r]   = make_float2(v.x, v.y);
            F[2*r+1] = make_float2(v.z, v.w);
        }
        bfly4_nw(F[0], F[4], F[8],  F[12]);
        bfly4(F[1], F[5], F[9],  F[13], make_float2(C1,-S1), make_float2(C2,-C2), make_float2(S1,-C1));
        bfly4(F[2], F[6], F[10], F[14], make_float2(C2,-C2), make_float2(0.f,-1.f), make_float2(-C2,-C2));
        bfly4(F[3], F[7], F[11], F[15], make_float2(S1,-C1), make_float2(-C2,-C2), make_float2(-C1, S1));
        bfly4_nw(F[0],  F[1],  F[2],  F[3]);
        bfly4_nw(F[4],  F[5],  F[6],  F[7]);
        bfly4_nw(F[8],  F[9],  F[10], F[11]);
        bfly4_nw(F[12], F[13], F[14], F[15]);
        #pragma unroll
        for (int r = 0; r < 8; ++r)
            p[r] = make_float4(F[2*r].x, F[2*r].y, F[2*r+1].x, F[2*r+1].y);
    }
    __syncthreads();   // the only block barrier: publish arrays for output

    // ---- output: unpack + mag/phase; 64-B write runs per (k, tile) ----
    const int kg  = tid >> 3;          // 0..63
    const int jj  = tid & 7;           // array == frame pair
    const int t_e = t0 + 2*jj;
    const bool tval = (t_e < NFRAMES); // pair-valid (NFRAMES even)

    const int R1 = ((kg & 3) << 8) | ((kg & 12) << 4) | (kg & 48);
    const int km = 64 - kg;
    const int R2 = ((km & 3) << 8) | ((km & 12) << 4) | (km & 48);
    const int J0 = (kg == 0) ? 16 : 15;
    const float2* zp1 = &zb[jj*ROW + PAD(R1)];
    const float2* zp2 = &zb[jj*ROW + PAD(R2)];

    float* magp = out;                                        // [32][513][622]
    float* php  = out + (size_t)NBATCH * KBINS * NFRAMES;     // [32][1024][622]
    const size_t magbase = (size_t)b * KBINS * NFRAMES + t_e;
    const size_t phbase  = (size_t)b * NFFT  * NFRAMES + t_e;

    float2 pm[8];   // buffered mirror phases (stored in a second pass)

    if (tval) {
        #pragma unroll
        for (int it = 0; it < 9; ++it) {
            if (it == 8 && kg != 0) break;             // only k=512 remains
            const int k  = kg + (it << 6);
            const int c1 = ((it & 3) << 2) | (it >> 2);            // rev4(64it)
            const int j2 = (J0 - it) & 15;
            const int c2 = ((j2 & 3) << 2) | (j2 >> 2);
            const float2 z1 = zp1[c1];
            const float2 z2 = zp2[c2];
            // F_even[k]=(Z[k]+conj(Z[N-k]))/2 ; F_odd[k]=-i(Z[k]-conj(Z[N-k]))/2
            const float re_e = 0.5f*(z1.x + z2.x);
            const float im_e = 0.5f*(z1.y - z2.y);     // exact +0.0 at k=0,512
            const float re_o = 0.5f*(z1.y + z2.y);
            const float im_o = 0.5f*(z2.x - z1.x);
            *reinterpret_cast<float2*>(&magp[magbase + (size_t)k * NFRAMES]) =
                make_float2(fmaf(re_e, re_e, im_e*im_e),
                            fmaf(re_o, re_o, im_o*im_o));
            const float ph_e = fast_atan2f(im_e, re_e);
            const float ph_o = fast_atan2f(im_o, re_o);
            *reinterpret_cast<float2*>(&php[phbase + (size_t)k * NFRAMES]) =
                make_float2(ph_e, ph_o);
            if (it < 8) pm[it] = make_float2(ph_e, ph_o);
        }
        // mirror bins (atan2 odd in y INCLUDING signed zeros -> sign flip),
        // issued as a second pass in ascending row order (it descending).
        #pragma unroll
        for (int it = 7; it >= 0; --it) {
            const int k = kg + (it << 6);
            if (k != 0) {
                *reinterpret_cast<float2*>(&php[phbase + (size_t)(NFFT - k) * NFRAMES]) =
                    make_float2(-pm[it].x, -pm[it].y);
            }
        }
    }
}

extern "C" void kernel_launch(void* const* d_in, const int* in_sizes, int n_in,
                              void* d_out, int out_size, void* d_ws, size_t ws_size,
                              hipStream_t stream) {
    const float* x  = (const float*)d_in[0];
    const float* rw = (const float*)d_in[1];   // row 0 = fp32 hanning window
    float* out = (float*)d_out;
    spec_kernel<<<dim3(NBLK, 1, 1), dim3(NT, 1, 1), 0, stream>>>(x, rw, out);
}